// Round 4
// baseline (35.363 us; speedup 1.0000x reference)
//
#include <hip/hip_runtime.h>
#include <math.h>

// Biquad peaking EQ over [B=8, C=2, T=1200000] f32.
// Round 4: same affine-scan algorithm as round 3, restructured for occupancy.
//  - 256-thread blocks = 4 INDEPENDENT waves, each owning one 2048-sample
//    segment (own 8 KB LDS slice). No __syncthreads anywhere: all LDS
//    dependencies are same-wave (LDS pipe is in-order per wave; compiler
//    inserts lgkmcnt waits; asm memory barriers stop reordering).
//  - Block LDS = 32 KB exactly -> 5 blocks/CU -> 20 waves/CU (62%), vs the
//    ~11 waves/CU the round-3 1-wave blocks achieved (wg-slot limited).
//  - alpha/beta propagated via __shfl (no LDS round-trip); c1/c2 correction
//    tables per-lane in registers (store-loop j = (lane*4)&31 is invariant).
// Per wave: stage 2048 x (coalesced float4, XOR-swizzled LDS scatter);
// zero-state biquad over own 32-sample row (in-place y over x); 6-step
// shfl_up affine scan of exit states; store with fused linear correction.
// Warm-up 4 rows (128 samples): truncation r^128*|state| ~ 1e-4; measured
// absmax 0.0156 in rounds 2-3 (threshold 0.119).

#define T_LEN 1200000
#define NCH   16
#define L     32
#define NR    64
#define NWARM 4
#define OUT_ROWS (NR - NWARM)           // 60
#define OUT_PER_SEG (OUT_ROWS * L)      // 1920
#define SEGS (T_LEN / OUT_PER_SEG)      // 625 (exact)
#define WAVE_FLOATS (NR * L)            // 2048
#define WPB   4                         // waves per block
#define NBLOCKS (SEGS * NCH / WPB)      // 2500

struct Params {
    float b0, b1, b2, a1, a2;
    float lnr, theta, inv_sinth;
    float C[6][4];                      // M^(L*2^k), row-major
};

__global__ __launch_bounds__(256, 5) void eq_kernel(const float* __restrict__ x,
                                                    float* __restrict__ y, Params P)
{
    __shared__ __align__(16) float lds[WPB * WAVE_FLOATS];   // 32 KB

    const int lane = threadIdx.x & 63;
    const int wid  = threadIdx.x >> 6;
    float* __restrict__ xs = lds + (wid << 11);

    const int wg  = blockIdx.x * WPB + wid;        // 0..9999
    const int ch  = wg / SEGS;
    const int seg = wg - ch * SEGS;
    const float* __restrict__ xc = x + (size_t)ch * T_LEN;
    float*       __restrict__ yc = y + (size_t)ch * T_LEN;
    const int g0 = seg * OUT_PER_SEG - NWARM * L;  // -128 for seg 0

    // ---- per-lane correction tables: t0 = (lane*4)&31, need phi(t0-1..t0+3)
    float c1r[4], c2r[4];
    {
        const int t0 = (lane << 2) & 31;
        float ph[5];
        #pragma unroll
        for (int k = 0; k < 5; ++k) {
            int t = t0 - 1 + k;
            ph[k] = (t < 0) ? 0.f
                            : expf(t * P.lnr) * sinf((t + 1) * P.theta) * P.inv_sinth;
        }
        #pragma unroll
        for (int k = 0; k < 4; ++k) {
            c1r[k] = fmaf(-P.a1, ph[k + 1], -P.a2 * ph[k]);  // resp. to y[-1]=1
            c2r[k] = -P.a2 * ph[k + 1];                      // resp. to y[-2]=1
        }
    }

    // ---- stage: coalesced float4 loads, swizzled LDS scatter ----
    #pragma unroll
    for (int it = 0; it < WAVE_FLOATS / 4 / 64; ++it) {      // 8
        int q = ((it << 6) + lane) << 2;
        int g = g0 + q;
        float4 val = make_float4(0.f, 0.f, 0.f, 0.f);
        if (g >= 0 && g < T_LEN) val = *(const float4*)(xc + g);
        int row = q >> 5, j = q & 31, m = row & 31, base = row << 5;
        xs[base + ((j + 0) ^ m)] = val.x;
        xs[base + ((j + 1) ^ m)] = val.y;
        xs[base + ((j + 2) ^ m)] = val.z;
        xs[base + ((j + 3) ^ m)] = val.w;
    }
    asm volatile("" ::: "memory");   // same-wave LDS RAW: keep program order

    // ---- phase A: zero-state biquad over own row, y_zs in place ----
    float v1 = 0.f, v2 = 0.f;
    {
        const int m = lane & 31, base = lane << 5;
        float x1 = 0.f, x2 = 0.f;
        if (lane > 0) {                 // prev row tail, read BEFORE overwrite
            int pb = (lane - 1) << 5, pm = (lane - 1) & 31;
            x1 = xs[pb + (31 ^ pm)];
            x2 = xs[pb + (30 ^ pm)];
        }
        asm volatile("" ::: "memory"); // don't sink these reads into the loop
        #pragma unroll 8
        for (int j = 0; j < L; ++j) {
            int w = base + (j ^ m);
            float xv = xs[w];
            float f  = fmaf(P.b0, xv, fmaf(P.b1, x1, P.b2 * x2));
            float t2 = fmaf(-P.a2, v2, f);
            float yv = fmaf(-P.a1, v1, t2);
            v2 = v1; v1 = yv;
            x2 = x1; x1 = xv;
            xs[w] = yv;
        }
    }

    // ---- inclusive affine scan across 64 lanes ----
    #pragma unroll
    for (int k = 0; k < 6; ++k) {
        int d = 1 << k;
        float p1 = __shfl_up(v1, d);
        float p2 = __shfl_up(v2, d);
        if (lane < d) { p1 = 0.f; p2 = 0.f; }
        float n1 = fmaf(P.C[k][0], p1, fmaf(P.C[k][1], p2, v1));
        float n2 = fmaf(P.C[k][2], p1, fmaf(P.C[k][3], p2, v2));
        v1 = n1; v2 = n2;
    }
    float e1 = __shfl_up(v1, 1);        // entry state of row `lane`
    float e2 = __shfl_up(v2, 1);
    if (lane == 0) { e1 = 0.f; e2 = 0.f; }
    asm volatile("" ::: "memory");      // y_zs writes precede store-phase reads

    // ---- store rows 4..63 with fused correction: coalesced float4 ----
    const int j = (lane << 2) & 31;     // invariant across iterations
    #pragma unroll
    for (int it = 0; it < 8; ++it) {
        int vo = (it << 6) + lane;      // < 480 except half of it=7
        int row = 4 + (it << 3) + (lane >> 3);
        row = row > 63 ? 63 : row;      // clamp for shfl (inactive tail lanes)
        float al = __shfl(e1, row);     // all 64 lanes active here
        float be = __shfl(e2, row);
        if (vo < OUT_PER_SEG / 4) {
            int m = row & 31, base = row << 5;
            float4 o;
            o.x = fmaf(al, c1r[0], fmaf(be, c2r[0], xs[base + ((j + 0) ^ m)]));
            o.y = fmaf(al, c1r[1], fmaf(be, c2r[1], xs[base + ((j + 1) ^ m)]));
            o.z = fmaf(al, c1r[2], fmaf(be, c2r[2], xs[base + ((j + 2) ^ m)]));
            o.w = fmaf(al, c1r[3], fmaf(be, c2r[3], xs[base + ((j + 3) ^ m)]));
            int q = (vo << 2) + NWARM * L;
            *(float4*)(yc + g0 + q) = o;   // g0+q in [seg*1920, seg*1920+1920)
        }
    }
}

extern "C" void kernel_launch(void* const* d_in, const int* in_sizes, int n_in,
                              void* d_out, int out_size, void* d_ws, size_t ws_size,
                              hipStream_t stream) {
    const float* x = (const float*)d_in[0];
    float* y = (float*)d_out;

    double w0    = 2.0 * M_PI * 1000.0 / 44100.0;
    double A     = exp(6.0 / 40.0 * log(10.0));
    double al    = sin(w0) / (2.0 * 0.707);
    double b0 = 1.0 + al * A;
    double b1 = -2.0 * cos(w0);
    double b2 = 1.0 - al * A;
    double a0 = 1.0 + al / A;
    double a1 = -2.0 * cos(w0);
    double a2 = 1.0 - al / A;
    b0 /= a0; b1 /= a0; b2 /= a0; a1 /= a0; a2 /= a0;

    Params P;
    P.b0 = (float)b0; P.b1 = (float)b1; P.b2 = (float)b2;
    P.a1 = (float)a1; P.a2 = (float)a2;

    double r     = sqrt(a2);
    double theta = acos(-a1 / (2.0 * r));
    P.lnr = (float)log(r);
    P.theta = (float)theta;
    P.inv_sinth = (float)(1.0 / sin(theta));

    double m00 = -a1, m01 = -a2, m10 = 1.0, m11 = 0.0;
    for (int s = 0; s < 5; ++s) {       // -> M^32
        double t00 = m00 * m00 + m01 * m10;
        double t01 = m00 * m01 + m01 * m11;
        double t10 = m10 * m00 + m11 * m10;
        double t11 = m10 * m01 + m11 * m11;
        m00 = t00; m01 = t01; m10 = t10; m11 = t11;
    }
    for (int k = 0; k < 6; ++k) {       // C[k] = M^(32*2^k)
        P.C[k][0] = (float)m00; P.C[k][1] = (float)m01;
        P.C[k][2] = (float)m10; P.C[k][3] = (float)m11;
        double t00 = m00 * m00 + m01 * m10;
        double t01 = m00 * m01 + m01 * m11;
        double t10 = m10 * m00 + m11 * m10;
        double t11 = m10 * m01 + m11 * m11;
        m00 = t00; m01 = t01; m10 = t10; m11 = t11;
    }

    eq_kernel<<<NBLOCKS, 256, 0, stream>>>(x, y, P);
}

// Round 5
// 29.529 us; speedup vs baseline: 1.1976x; 1.1976x over previous
//
#include <hip/hip_runtime.h>
#include <math.h>

// Biquad peaking EQ over [B=8, C=2, T=1200000] f32.
// Round 5: 2-deep software pipeline (persistent waves, reg-staged tiles) +
// padded-stride LDS with b128 ops.
//  - 5000 waves (1250 blocks x 4), each owns segments w and w+5000.
//    Both segments' global loads are issued up front; stage(ra) waits with a
//    counted vmcnt (rb stays in flight through all of segment A's compute).
//  - LDS row stride 36 words (pad +4): every access pattern (stage write,
//    own-row b128 read/write, correction b128 read) hits each bank exactly
//    8x per wave op = the b128 minimum. No XOR swizzle needed -> clean
//    ds_read_b128/ds_write_b128 with immediate offsets.
//  - Nontemporal float4 output stores (output is never re-read).
// Algorithm per wave-segment (as round 3/4): zero-state biquad over each
// lane's 32-sample row (in-place y over x), 6-step shfl_up affine scan of
// exit states with precomputed M^(32*2^k), then fused linear correction
// y = y_zs + alpha*c1[t] + beta*c2[t] in the coalesced store pass.
// Warm-up 4 rows = 128 samples: truncation ~1e-4; measured absmax 0.0156.

typedef float f32x4 __attribute__((ext_vector_type(4)));

#define T_LEN 1200000
#define NCH   16
#define L     32
#define NR    64
#define NWARM 4
#define OUT_ROWS (NR - NWARM)           // 60
#define OUT_PER_SEG (OUT_ROWS * L)      // 1920
#define SEGS (T_LEN / OUT_PER_SEG)      // 625 (exact)
#define WPB 4
#define NBLOCKS 1250
#define NWAVES (NBLOCKS * WPB)          // 5000 waves x 2 segments = 10000
#define RSTRIDE 36                      // words per row (pad 4) -> minimal b128 banking
#define WAVE_LDS (NR * RSTRIDE)         // 2304 words = 9216 B per wave

struct Params {
    float b0, b1, b2, a1, a2;
    float lnr, theta, inv_sinth;
    float C[6][4];                      // M^(L*2^k), row-major
};

__device__ __forceinline__ void load_seg(f32x4 r[8], const float* __restrict__ xc,
                                         int g0, int lane)
{
    #pragma unroll
    for (int it = 0; it < 8; ++it) {
        int g = g0 + (it << 8) + (lane << 2);     // sample index, multiple of 4
        f32x4 v = {0.f, 0.f, 0.f, 0.f};
        if (g >= 0 && g < T_LEN) v = *(const f32x4*)(xc + g);
        r[it] = v;
    }
}

__device__ __forceinline__ void stage_seg(float* __restrict__ xs, const f32x4 r[8],
                                          int lane)
{
    const int row0 = lane >> 3, j = (lane & 7) << 2;
    #pragma unroll
    for (int it = 0; it < 8; ++it) {
        int row = (it << 3) + row0;               // matches load_seg's q = it*256+lane*4
        *(f32x4*)&xs[row * RSTRIDE + j] = r[it];
    }
}

__device__ __forceinline__ void process_seg(float* __restrict__ xs,
                                            float* __restrict__ yc, int g0, int lane,
                                            const Params& P,
                                            const float c1r[4], const float c2r[4])
{
    const int base = lane * RSTRIDE;

    // prev row's x tail — read BEFORE any in-place y write (same-wave LDS is
    // in-order; asm barrier stops the compiler sinking these reads)
    float x1 = 0.f, x2 = 0.f;
    if (lane > 0) {
        x1 = xs[base - RSTRIDE + 31];
        x2 = xs[base - RSTRIDE + 30];
    }
    asm volatile("" ::: "memory");

    // zero-state biquad over own row, y written in place (b128 in/out)
    float v1 = 0.f, v2 = 0.f;
    #pragma unroll
    for (int b = 0; b < 8; ++b) {
        f32x4 xv = *(const f32x4*)&xs[base + (b << 2)];
        f32x4 yv;
        #pragma unroll
        for (int k = 0; k < 4; ++k) {
            float xk = xv[k];
            float f  = fmaf(P.b0, xk, fmaf(P.b1, x1, P.b2 * x2));
            float t2 = fmaf(-P.a2, v2, f);
            float yk = fmaf(-P.a1, v1, t2);
            v2 = v1; v1 = yk;
            x2 = x1; x1 = xk;
            yv[k] = yk;
        }
        *(f32x4*)&xs[base + (b << 2)] = yv;
    }

    // inclusive affine scan of exit states across 64 lanes
    #pragma unroll
    for (int k = 0; k < 6; ++k) {
        int d = 1 << k;
        float p1 = __shfl_up(v1, d);
        float p2 = __shfl_up(v2, d);
        if (lane < d) { p1 = 0.f; p2 = 0.f; }
        float n1 = fmaf(P.C[k][0], p1, fmaf(P.C[k][1], p2, v1));
        float n2 = fmaf(P.C[k][2], p1, fmaf(P.C[k][3], p2, v2));
        v1 = n1; v2 = n2;
    }
    float e1 = __shfl_up(v1, 1);                 // entry state of row `lane`
    float e2 = __shfl_up(v2, 1);
    if (lane == 0) { e1 = 0.f; e2 = 0.f; }

    // store rows 4..63 with fused correction: coalesced nontemporal float4
    const int j0 = (lane << 2) & 31;
    #pragma unroll
    for (int it = 0; it < 8; ++it) {
        int vo = (it << 6) + lane;
        int row = NWARM + (it << 3) + (lane >> 3);
        row = row > 63 ? 63 : row;               // clamp for shfl on tail lanes
        float al = __shfl(e1, row);
        float be = __shfl(e2, row);
        if (vo < OUT_PER_SEG / 4) {
            f32x4 yv = *(const f32x4*)&xs[row * RSTRIDE + j0];
            f32x4 o;
            #pragma unroll
            for (int k = 0; k < 4; ++k)
                o[k] = fmaf(al, c1r[k], fmaf(be, c2r[k], yv[k]));
            int q = (vo << 2) + NWARM * L;
            __builtin_nontemporal_store(o, (f32x4*)(yc + g0 + q));
        }
    }
}

__global__ __launch_bounds__(256, 4) void eq_kernel(const float* __restrict__ x,
                                                    float* __restrict__ y, Params P)
{
    __shared__ __align__(16) float lds[WPB * WAVE_LDS];   // 36864 B
    const int lane = threadIdx.x & 63;
    const int wid  = threadIdx.x >> 6;
    float* xs = lds + wid * WAVE_LDS;
    const int w = blockIdx.x * WPB + wid;

    // per-lane correction tables (once per wave, reused for both segments)
    float c1r[4], c2r[4];
    {
        const int t0 = (lane << 2) & 31;
        float ph[5];
        #pragma unroll
        for (int k = 0; k < 5; ++k) {
            int t = t0 - 1 + k;
            ph[k] = (t < 0) ? 0.f
                            : expf(t * P.lnr) * sinf((t + 1) * P.theta) * P.inv_sinth;
        }
        #pragma unroll
        for (int k = 0; k < 4; ++k) {
            c1r[k] = fmaf(-P.a1, ph[k + 1], -P.a2 * ph[k]);  // resp. to y[-1]=1
            c2r[k] = -P.a2 * ph[k + 1];                      // resp. to y[-2]=1
        }
    }

    const int sA = w, sB = w + NWAVES;
    const int chA = sA / SEGS, segA = sA - chA * SEGS;
    const int chB = sB / SEGS, segB = sB - chB * SEGS;
    const int g0A = segA * OUT_PER_SEG - NWARM * L;          // -128 only for seg 0
    const int g0B = segB * OUT_PER_SEG - NWARM * L;
    const float* xcA = x + (size_t)chA * T_LEN;
    const float* xcB = x + (size_t)chB * T_LEN;
    float* ycA = y + (size_t)chA * T_LEN;
    float* ycB = y + (size_t)chB * T_LEN;

    f32x4 ra[8], rb[8];
    load_seg(ra, xcA, g0A, lane);     // in flight
    load_seg(rb, xcB, g0B, lane);     // in flight through all of segment A
    stage_seg(xs, ra, lane);          // counted vmcnt: waits ra only
    asm volatile("" ::: "memory");
    process_seg(xs, ycA, g0A, lane, P, c1r, c2r);
    stage_seg(xs, rb, lane);          // rb landed long ago
    asm volatile("" ::: "memory");
    process_seg(xs, ycB, g0B, lane, P, c1r, c2r);
}

extern "C" void kernel_launch(void* const* d_in, const int* in_sizes, int n_in,
                              void* d_out, int out_size, void* d_ws, size_t ws_size,
                              hipStream_t stream) {
    const float* x = (const float*)d_in[0];
    float* y = (float*)d_out;

    // torchaudio peaking-EQ coefficients (double, then cast — matches ref)
    double w0    = 2.0 * M_PI * 1000.0 / 44100.0;
    double A     = exp(6.0 / 40.0 * log(10.0));
    double al    = sin(w0) / (2.0 * 0.707);
    double b0 = 1.0 + al * A;
    double b1 = -2.0 * cos(w0);
    double b2 = 1.0 - al * A;
    double a0 = 1.0 + al / A;
    double a1 = -2.0 * cos(w0);
    double a2 = 1.0 - al / A;
    b0 /= a0; b1 /= a0; b2 /= a0; a1 /= a0; a2 /= a0;

    Params P;
    P.b0 = (float)b0; P.b1 = (float)b1; P.b2 = (float)b2;
    P.a1 = (float)a1; P.a2 = (float)a2;

    double r     = sqrt(a2);
    double theta = acos(-a1 / (2.0 * r));
    P.lnr = (float)log(r);
    P.theta = (float)theta;
    P.inv_sinth = (float)(1.0 / sin(theta));

    double m00 = -a1, m01 = -a2, m10 = 1.0, m11 = 0.0;
    for (int s = 0; s < 5; ++s) {       // -> M^32
        double t00 = m00 * m00 + m01 * m10;
        double t01 = m00 * m01 + m01 * m11;
        double t10 = m10 * m00 + m11 * m10;
        double t11 = m10 * m01 + m11 * m11;
        m00 = t00; m01 = t01; m10 = t10; m11 = t11;
    }
    for (int k = 0; k < 6; ++k) {       // C[k] = M^(32*2^k)
        P.C[k][0] = (float)m00; P.C[k][1] = (float)m01;
        P.C[k][2] = (float)m10; P.C[k][3] = (float)m11;
        double t00 = m00 * m00 + m01 * m10;
        double t01 = m00 * m01 + m01 * m11;
        double t10 = m10 * m00 + m11 * m10;
        double t11 = m10 * m01 + m11 * m11;
        m00 = t00; m01 = t01; m10 = t10; m11 = t11;
    }

    eq_kernel<<<NBLOCKS, 256, 0, stream>>>(x, y, P);
}